// Round 2
// 664.600 us; speedup vs baseline: 1.0863x; 1.0863x over previous
//
#include <hip/hip_runtime.h>

#define NUM_GENES 20000
#define NUM_FEAT  256
#define BATCH     32
#define VOCAB     9

// clang native vector type — accepted by __builtin_nontemporal_store
// (HIP's float4 is a struct and is rejected).
typedef float f32x4 __attribute__((ext_vector_type(4)));

// Single-block kernel: zero the per-gene flag array (vectorized int4),
// then scatter the masked geneset. Races on flag writes are benign
// (all write 1).
__global__ void build_flags_kernel(const int* __restrict__ geneset,
                                   int n_mask,
                                   int* __restrict__ flags) {
    // 20000 ints = 5000 int4
    int4* f4 = (int4*)flags;
    const int4 z = make_int4(0, 0, 0, 0);
    for (int i = threadIdx.x; i < NUM_GENES / 4; i += blockDim.x) f4[i] = z;
    __syncthreads();
    for (int i = threadIdx.x; i < n_mask; i += blockDim.x) {
        int g = geneset[i];
        if (g >= 0 && g < NUM_GENES) flags[g] = 1;
    }
}

// out[b,g,f] = gene_table[g,f] + mut_table[flags[g] ? 8 : X[b,g], f]
//
// Gene-major decomposition: one WAVE owns one gene row g and iterates all
// 32 batches. The gene_table row (256 f32 = 64 float4 = one float4/lane)
// is loaded ONCE into registers and reused 32x — read traffic drops from
// ~655 MB (batch-major re-stream) to ~23 MB, making the kernel pure-write.
// mut_table (9 KB) is L1-resident. X[b*G+g] is wave-uniform (one fetch).
// Stores are 1 KB contiguous per wave-iteration, nontemporal so the
// 655 MB write stream doesn't evict cached reads.
__global__ __launch_bounds__(256) void add_emb_kernel(
        const float* __restrict__ gene_table,  // [G,256] f32
        const float* __restrict__ mut_table,   // [9,256]  f32
        const int*   __restrict__ X,           // [B,G]
        const int*   __restrict__ flags,       // [G]
        float*       __restrict__ out)         // [B,G,256] f32
{
    const int wid  = threadIdx.x >> 6;   // wave in block: 0..3
    const int lane = threadIdx.x & 63;   // one float4 of the 256-f row
    const int g    = blockIdx.x * 4 + wid;   // grid = 5000 blocks exactly

    const f32x4* gt = (const f32x4*)gene_table;
    const f32x4* mt = (const f32x4*)mut_table;
    f32x4*       o  = (f32x4*)out;

    const f32x4 a   = gt[(size_t)g * 64 + lane];   // gene row, in regs
    const int   flg = flags[g];                    // wave-uniform

    if (flg) {
        // Masked gene: same sum for every batch — compute once, stream 32
        // identical 1 KB stores.
        const f32x4 r = a + mt[(size_t)(VOCAB - 1) * 64 + lane];
#pragma unroll
        for (int b = 0; b < BATCH; ++b) {
            __builtin_nontemporal_store(
                r, &o[((size_t)b * NUM_GENES + g) * 64 + lane]);
        }
    } else {
#pragma unroll
        for (int b = 0; b < BATCH; ++b) {
            const int tok = X[(size_t)b * NUM_GENES + g];  // wave-uniform
            const f32x4 r = a + mt[(size_t)tok * 64 + lane];  // L1 hit
            __builtin_nontemporal_store(
                r, &o[((size_t)b * NUM_GENES + g) * 64 + lane]);
        }
    }
}

extern "C" void kernel_launch(void* const* d_in, const int* in_sizes, int n_in,
                              void* d_out, int out_size, void* d_ws, size_t ws_size,
                              hipStream_t stream) {
    // setup_inputs() order:
    // 0: X_converted   [32,20000] int32
    // 1: mask_percentage (scalar, unused — test_geneset branch)
    // 2: test_geneset  [2000] int32
    // 3: gene_table    [20000,256] float32
    // 4: mut_table     [9,256]     float32
    const int*   X          = (const int*)d_in[0];
    const int*   geneset    = (const int*)d_in[2];
    const float* gene_table = (const float*)d_in[3];
    const float* mut_table  = (const float*)d_in[4];
    const int    n_mask     = in_sizes[2];

    int*   flags = (int*)d_ws;   // 20000 * 4 B = 80 KB scratch
    float* out   = (float*)d_out;

    build_flags_kernel<<<1, 1024, 0, stream>>>(geneset, n_mask, flags);
    // 20000 genes / 4 waves per block = 5000 blocks
    add_emb_kernel<<<NUM_GENES / 4, 256, 0, stream>>>(
        gene_table, mut_table, X, flags, out);
}

// Round 3
// 660.098 us; speedup vs baseline: 1.0937x; 1.0068x over previous
//
#include <hip/hip_runtime.h>

#define NUM_GENES 20000
#define NUM_FEAT  256
#define BATCH     32
#define VOCAB     9

// clang native vector type (HIP float4 is a struct; this compiles to
// global_load_dwordx4 / global_store_dwordx4).
typedef float f32x4 __attribute__((ext_vector_type(4)));

// Scatter the masked geneset into the (already-zeroed) flag array.
// Races on flag writes are benign (all write 1).
__global__ void scatter_flags_kernel(const int* __restrict__ geneset,
                                     int n_mask,
                                     int* __restrict__ flags) {
    const int i = blockIdx.x * blockDim.x + threadIdx.x;
    if (i < n_mask) {
        int g = geneset[i];
        if (g >= 0 && g < NUM_GENES) flags[g] = 1;
    }
}

// out[b,g,f] = gene_table[g,f] + mut_table[flags[g] ? 8 : X[b,g], f]
//
// Gene-major decomposition: one WAVE owns one gene row g and iterates all
// 32 batches. The gene_table row (one float4/lane) is loaded ONCE into
// registers and reused 32x — read traffic is ~23 MB; the kernel is
// pure-write. mut_table (9 KB) is L1-resident. X[b*G+g] is wave-uniform.
//
// Round-2 lesson: nontemporal stores ran the write stream at ~2.7 TB/s;
// the harness fill proves plain stores reach 6.3 TB/s. Use PLAIN stores.
// All 32 wave-uniform token loads are prefetched into registers so the
// store loop issues without dependent-load stalls.
__global__ __launch_bounds__(256) void add_emb_kernel(
        const float* __restrict__ gene_table,  // [G,256] f32
        const float* __restrict__ mut_table,   // [9,256]  f32
        const int*   __restrict__ X,           // [B,G]
        const int*   __restrict__ flags,       // [G]
        float*       __restrict__ out)         // [B,G,256] f32
{
    const int wid  = threadIdx.x >> 6;   // wave in block: 0..3
    const int lane = threadIdx.x & 63;   // one float4 of the 256-f row
    const int g    = blockIdx.x * 4 + wid;   // grid = 5000 blocks exactly

    const f32x4* gt = (const f32x4*)gene_table;
    const f32x4* mt = (const f32x4*)mut_table;
    f32x4*       o  = (f32x4*)out;

    const f32x4 a   = gt[(size_t)g * 64 + lane];   // gene row, in regs
    const int   flg = flags[g];                    // wave-uniform

    if (flg) {
        // Masked gene: same sum for every batch — compute once, stream 32
        // identical 1 KB stores.
        const f32x4 r = a + mt[(size_t)(VOCAB - 1) * 64 + lane];
#pragma unroll
        for (int b = 0; b < BATCH; ++b) {
            o[((size_t)b * NUM_GENES + g) * 64 + lane] = r;
        }
    } else {
        // Prefetch all 32 wave-uniform tokens (independent addresses —
        // issue back-to-back, one latency for all).
        int tok[BATCH];
#pragma unroll
        for (int b = 0; b < BATCH; ++b) {
            tok[b] = X[(size_t)b * NUM_GENES + g];
        }
#pragma unroll
        for (int b = 0; b < BATCH; ++b) {
            const f32x4 r = a + mt[(size_t)tok[b] * 64 + lane];  // L1 hit
            o[((size_t)b * NUM_GENES + g) * 64 + lane] = r;
        }
    }
}

extern "C" void kernel_launch(void* const* d_in, const int* in_sizes, int n_in,
                              void* d_out, int out_size, void* d_ws, size_t ws_size,
                              hipStream_t stream) {
    // setup_inputs() order:
    // 0: X_converted   [32,20000] int32
    // 1: mask_percentage (scalar, unused — test_geneset branch)
    // 2: test_geneset  [2000] int32
    // 3: gene_table    [20000,256] float32
    // 4: mut_table     [9,256]     float32
    const int*   X          = (const int*)d_in[0];
    const int*   geneset    = (const int*)d_in[2];
    const float* gene_table = (const float*)d_in[3];
    const float* mut_table  = (const float*)d_in[4];
    const int    n_mask     = in_sizes[2];

    int*   flags = (int*)d_ws;   // 20000 * 4 B = 80 KB scratch
    float* out   = (float*)d_out;

    // Zero flags via the fill engine (parallel, ~2 us), then a tiny
    // scatter kernel. Replaces the single-block serial build_flags.
    hipMemsetAsync(flags, 0, NUM_GENES * sizeof(int), stream);
    scatter_flags_kernel<<<(n_mask + 1023) / 1024, 1024, 0, stream>>>(
        geneset, n_mask, flags);

    // 20000 genes / 4 waves per block = 5000 blocks
    add_emb_kernel<<<NUM_GENES / 4, 256, 0, stream>>>(
        gene_table, mut_table, X, flags, out);
}